// Round 6
// baseline (395.343 us; speedup 1.0000x reference)
//
#include <hip/hip_runtime.h>
#include <hip/hip_cooperative_groups.h>
#include <hip/hip_bf16.h>
#include <float.h>
#include <math.h>

namespace cg = cooperative_groups;

#define BB 64
#define NNtok 197
#define DD 768
#define HH 12
#define PP 12
#define CC 200
#define NPATCH 196
#define SMB 21632

typedef short bf16x8 __attribute__((ext_vector_type(8)));
typedef float f32x4 __attribute__((ext_vector_type(4)));

__device__ __forceinline__ unsigned short bf16_bits(float x) {
  __hip_bfloat16 h = __float2bfloat16(x);
  return *reinterpret_cast<unsigned short*>(&h);
}
__device__ __forceinline__ float u2f(unsigned int u) {
  union { unsigned int u; float f; } cv; cv.u = u; return cv.f;
}
__device__ __forceinline__ float bf16_val(const __hip_bfloat16* p) {
  return __bfloat162float(*p);
}

// ---------- GEMM 64x64 tile: C = A(MxK) @ W(NxK)^T + bias ; 4 waves 2x2 -----
template <int RELU, int OUTBF>
__device__ __forceinline__ void gemm_tile64(
    const __hip_bfloat16* __restrict__ A, const __hip_bfloat16* __restrict__ W,
    const float* __restrict__ bias, void* __restrict__ Cd, int Nn, int Kk,
    int mt, int nt, int t) {
  int wave = t >> 6, lane = t & 63;
  int wm = wave >> 1, wn = wave & 1;
  int row0 = mt * 64 + wm * 32;
  int col0 = nt * 64 + wn * 32;
  int lr = lane & 15;
  int kg = lane >> 4;
  f32x4 acc[2][2];
#pragma unroll
  for (int i = 0; i < 2; i++)
#pragma unroll
    for (int j = 0; j < 2; j++) {
      acc[i][j][0] = 0.f; acc[i][j][1] = 0.f;
      acc[i][j][2] = 0.f; acc[i][j][3] = 0.f;
    }
  const __hip_bfloat16* Ab = A + (size_t)(row0 + lr) * Kk + kg * 8;
  const __hip_bfloat16* Wb = W + (size_t)(col0 + lr) * Kk + kg * 8;
  for (int k0 = 0; k0 < Kk; k0 += 32) {
    bf16x8 af[2], wf[2];
#pragma unroll
    for (int i = 0; i < 2; i++)
      af[i] = *(const bf16x8*)(Ab + (size_t)i * 16 * Kk + k0);
#pragma unroll
    for (int j = 0; j < 2; j++)
      wf[j] = *(const bf16x8*)(Wb + (size_t)j * 16 * Kk + k0);
#pragma unroll
    for (int i = 0; i < 2; i++)
#pragma unroll
      for (int j = 0; j < 2; j++)
        acc[i][j] = __builtin_amdgcn_mfma_f32_16x16x32_bf16(af[i], wf[j],
                                                            acc[i][j], 0, 0, 0);
  }
#pragma unroll
  for (int i = 0; i < 2; i++) {
#pragma unroll
    for (int j = 0; j < 2; j++) {
      int r0 = row0 + i * 16 + kg * 4;
      int c = col0 + j * 16 + lr;
      float bv = bias[c];
#pragma unroll
      for (int r = 0; r < 4; r++) {
        float v = acc[i][j][r] + bv;
        if (RELU) v = fmaxf(v, 0.f);
        if (OUTBF)
          ((__hip_bfloat16*)Cd)[(size_t)(r0 + r) * Nn + c] = __float2bfloat16(v);
        else
          ((float*)Cd)[(size_t)(r0 + r) * Nn + c] = v;
      }
    }
  }
}

// ---------- select + top-12 + gather + LN1 for batch b ----------------------
__device__ __forceinline__ void dev_select_ln1(
    int b, int t, const float* __restrict__ hidden,
    const float* __restrict__ attns, const float* __restrict__ g,
    const float* __restrict__ be, __hip_bfloat16* __restrict__ parts,
    char* smraw) {
  float* sc = (float*)smraw;           // 256 f32
  int* sel_s = (int*)(smraw + 1024);   // 12 int
  int wv = t >> 6, ln = t & 63;
  float acc = -FLT_MAX;
  if (t < NPATCH) {
    acc = 0.f;
#pragma unroll
    for (int l = 0; l < 4; l++) {
      float part = 0.f;
#pragma unroll
      for (int h = 0; h < HH; h++) {
        size_t base = (size_t)((l * BB + b) * HH + h) * ((size_t)NNtok * NNtok);
        part += attns[base + 1 + t];
      }
      acc += part * (1.f / 12.f);
    }
    acc *= 0.25f;
  }
  sc[t] = acc;
  __syncthreads();
  if (t < 64) {
    float v[4]; int idx[4];
#pragma unroll
    for (int j = 0; j < 4; j++) { idx[j] = t + j * 64; v[j] = sc[idx[j]]; }
    for (int it = 0; it < PP; ++it) {
      float bv = v[0]; int bidx = idx[0];
#pragma unroll
      for (int j = 1; j < 4; j++)
        if (v[j] > bv || (v[j] == bv && idx[j] < bidx)) { bv = v[j]; bidx = idx[j]; }
      float cv = bv; int ci = bidx;
#pragma unroll
      for (int off = 32; off > 0; off >>= 1) {
        float ov = __shfl_xor(cv, off); int oi = __shfl_xor(ci, off);
        if (ov > cv || (ov == cv && oi < ci)) { cv = ov; ci = oi; }
      }
      if (t == 0) sel_s[it] = ci;
#pragma unroll
      for (int j = 0; j < 4; j++)
        if (idx[j] == ci) v[j] = -FLT_MAX;
    }
  }
  __syncthreads();
#pragma unroll
  for (int q = 0; q < 3; q++) {
    int i = wv * 3 + q;
    const float* row = hidden + ((size_t)b * NNtok + 1 + sel_s[i]) * DD;
    float x[12], s1 = 0.f, s2 = 0.f;
#pragma unroll
    for (int k = 0; k < 12; k++) {
      x[k] = row[ln + 64 * k];
      s1 += x[k]; s2 += x[k] * x[k];
    }
#pragma unroll
    for (int off = 32; off > 0; off >>= 1) {
      s1 += __shfl_xor(s1, off); s2 += __shfl_xor(s2, off);
    }
    float m = s1 * (1.f / DD);
    float rstd = rsqrtf(s2 * (1.f / DD) - m * m + 1e-5f);
    __hip_bfloat16* outp_ = parts + ((size_t)b * PP + i) * DD;
#pragma unroll
    for (int k = 0; k < 12; k++) {
      int d = ln + 64 * k;
      outp_[d] = __float2bfloat16((x[k] - m) * rstd * g[d] + be[d]);
    }
  }
}

// ---------- tiny attention for one (b,h) task -------------------------------
__device__ __forceinline__ void dev_attn(
    int task, int t, const __hip_bfloat16* __restrict__ qkv,
    __hip_bfloat16* __restrict__ o, char* smraw) {
  float* qs = (float*)smraw;    // 768
  float* ks = qs + 768;
  float* vs = ks + 768;
  float* smx = vs + 768;        // 144
  int b = task / HH, h = task % HH;
  for (int u = t; u < 768; u += 256) {
    int p = u >> 6, d = u & 63;
    size_t base = ((size_t)(b * PP + p)) * 2304 + h * 64 + d;
    qs[u] = bf16_val(qkv + base);
    ks[u] = bf16_val(qkv + base + 768);
    vs[u] = bf16_val(qkv + base + 1536);
  }
  __syncthreads();
  if (t < 144) {
    int i = t / 12, j = t % 12;
    float s = 0.f;
#pragma unroll
    for (int d = 0; d < 64; d++) s += qs[i * 64 + d] * ks[j * 64 + d];
    smx[i * 12 + j] = s * 0.125f;
  }
  __syncthreads();
  if (t < 12) {
    float m = -FLT_MAX;
    for (int j = 0; j < 12; j++) m = fmaxf(m, smx[t * 12 + j]);
    float e[12], sum = 0.f;
    for (int j = 0; j < 12; j++) { e[j] = expf(smx[t * 12 + j] - m); sum += e[j]; }
    float inv = 1.f / sum;
    for (int j = 0; j < 12; j++) smx[t * 12 + j] = e[j] * inv;
  }
  __syncthreads();
  for (int u = t; u < 768; u += 256) {
    int i = u >> 6, d = u & 63;
    float s = 0.f;
#pragma unroll
    for (int j = 0; j < 12; j++) s += smx[i * 12 + j] * vs[j * 64 + d];
    o[((size_t)(b * PP + i)) * DD + h * 64 + d] = __float2bfloat16(s);
  }
  __syncthreads();
}

// ---------- LN2 + pool softmax + weighted sum + MLP GEMV + ReLU (batch b) ---
__device__ __forceinline__ void dev_head(
    int b, int t, const float* __restrict__ aout, const float* __restrict__ g,
    const float* __restrict__ be, const float* __restrict__ wp,
    const float* __restrict__ bp, const float* __restrict__ ptemp,
    const __hip_bfloat16* __restrict__ wmlp, const float* __restrict__ bmlp,
    float* __restrict__ pmlp, char* smraw) {
  int wv = t >> 6, ln = t & 63;
  __hip_bfloat16* ybuf = (__hip_bfloat16*)smraw;  // 12*768 bf16 = 18432 B
  float* raww_s = (float*)(smraw + 18432);        // 12 f32
  float* pfeat = (float*)(smraw + 18496);         // 768 f32
#pragma unroll
  for (int q = 0; q < 3; q++) {
    int r = wv * 3 + q;
    const float* row = aout + ((size_t)(b * PP + r)) * DD;
    float x[12], s1 = 0.f, s2 = 0.f;
#pragma unroll
    for (int k = 0; k < 12; k++) {
      x[k] = row[ln + 64 * k];
      s1 += x[k]; s2 += x[k] * x[k];
    }
#pragma unroll
    for (int off = 32; off > 0; off >>= 1) {
      s1 += __shfl_xor(s1, off); s2 += __shfl_xor(s2, off);
    }
    float m = s1 * (1.f / DD);
    float rstd = rsqrtf(s2 * (1.f / DD) - m * m + 1e-5f);
    float pl = 0.f;
#pragma unroll
    for (int k = 0; k < 12; k++) {
      int d = ln + 64 * k;
      float y = (x[k] - m) * rstd * g[d] + be[d];
      ybuf[r * 768 + d] = __float2bfloat16(y);
      pl += y * wp[d];
    }
#pragma unroll
    for (int off = 32; off > 0; off >>= 1) pl += __shfl_xor(pl, off);
    if (ln == 0) raww_s[r] = pl + bp[0];
  }
  __syncthreads();
  float wts[12];
  {
    float inv = 1.f / fmaxf(ptemp[0], 0.3f);
    float z[12], mx = -FLT_MAX;
#pragma unroll
    for (int p = 0; p < 12; p++) { z[p] = raww_s[p] * inv; mx = fmaxf(mx, z[p]); }
    float s = 0.f;
#pragma unroll
    for (int p = 0; p < 12; p++) { z[p] = expf(z[p] - mx); s += z[p]; }
    float is = 1.f / s;
#pragma unroll
    for (int p = 0; p < 12; p++) wts[p] = z[p] * is;
  }
  for (int d = t; d < DD; d += 256) {
    float s = 0.f;
#pragma unroll
    for (int p = 0; p < 12; p++) s += __bfloat162float(ybuf[p * 768 + d]) * wts[p];
    pfeat[d] = s;
  }
  __syncthreads();
  for (int j = t; j < DD; j += 256) {
    const uint4* wr = (const uint4*)(wmlp + (size_t)j * DD);
    float acc2 = bmlp[j];
    for (int k = 0; k < 96; k++) {
      uint4 w4 = wr[k];
      const float* pf = &pfeat[k * 8];
      acc2 += pf[0] * u2f(w4.x << 16) + pf[1] * u2f(w4.x & 0xFFFF0000u)
            + pf[2] * u2f(w4.y << 16) + pf[3] * u2f(w4.y & 0xFFFF0000u)
            + pf[4] * u2f(w4.z << 16) + pf[5] * u2f(w4.z & 0xFFFF0000u)
            + pf[6] * u2f(w4.w << 16) + pf[7] * u2f(w4.w & 0xFFFF0000u);
    }
    pmlp[(size_t)b * DD + j] = fmaxf(acc2, 0.f);
  }
  __syncthreads();
}

// ---------- ArcFace: load fusion vec (per block), compute one cblk ----------
__device__ __forceinline__ float dev_arc_load(
    int b, int t, const float* __restrict__ hidden,
    const float* __restrict__ pmlp, char* smraw) {
  float4* fs4 = (float4*)smraw;          // 384 float4
  float* a4 = (float*)(smraw + 6144);    // 4
  int wv = t >> 6, ln = t & 63;
  const float4* cls4 = (const float4*)(hidden + (size_t)b * NNtok * DD);
  const float4* pm4 = (const float4*)(pmlp + (size_t)b * DD);
  for (int u = t; u < 384; u += 256) fs4[u] = (u < 192) ? cls4[u] : pm4[u - 192];
  __syncthreads();
  float s = 0.f;
  for (int u = t; u < 384; u += 256) {
    float4 v = fs4[u];
    s += v.x * v.x + v.y * v.y + v.z * v.z + v.w * v.w;
  }
#pragma unroll
  for (int off = 32; off > 0; off >>= 1) s += __shfl_xor(s, off);
  if (ln == 0) a4[wv] = s;
  __syncthreads();
  return rsqrtf(a4[0] + a4[1] + a4[2] + a4[3]);
}

__device__ __forceinline__ void dev_arc_cblk(
    int cblk, int b, float rnf, int t, const float* __restrict__ aw,
    const int* __restrict__ labels, float* __restrict__ out, char* smraw) {
  float4* fs4 = (float4*)smraw;
  int wv = t >> 6, ln = t & 63;
  int lab = labels[b];
  const float cos_m = 0.8775825618903728f, sin_m = 0.479425538604203f;
  const float th = -0.8775825618903728f, mm = 0.2397127693021015f;
#pragma unroll
  for (int ci = 0; ci < 2; ci++) {
    int c = cblk * 8 + wv + ci * 4;
    const float4* wr = (const float4*)(aw + (size_t)c * 1536);
    float acc = 0.f, nw = 0.f;
#pragma unroll
    for (int k = 0; k < 6; k++) {
      float4 a = fs4[ln + 64 * k];
      float4 w = wr[ln + 64 * k];
      acc += a.x * w.x + a.y * w.y + a.z * w.z + a.w * w.w;
      nw += w.x * w.x + w.y * w.y + w.z * w.z + w.w * w.w;
    }
#pragma unroll
    for (int off = 32; off > 0; off >>= 1) {
      acc += __shfl_xor(acc, off); nw += __shfl_xor(nw, off);
    }
    if (ln == 0) {
      float cosv = acc * rsqrtf(nw) * rnf;
      float s2 = 1.f - cosv * cosv;
      s2 = fminf(fmaxf(s2, 0.f), 1.f);
      float sinv = sqrtf(s2);
      float phi = cosv * cos_m - sinv * sin_m;
      phi = (cosv > th) ? phi : (cosv - mm);
      out[(size_t)b * CC + c] = ((c == lab) ? phi : cosv) * 30.f;
    }
  }
}

// ================= cooperative mega-kernel ==================================
__global__ __launch_bounds__(256) void k_mega(
    const float* __restrict__ hidden, const float* __restrict__ attns,
    const int* __restrict__ labels, const float* __restrict__ ln1_g,
    const float* __restrict__ ln1_b, const float* __restrict__ w_in,
    const float* __restrict__ b_in, const float* __restrict__ w_out,
    const float* __restrict__ b_out, const float* __restrict__ ln2_g,
    const float* __restrict__ ln2_b, const float* __restrict__ w_pool,
    const float* __restrict__ b_pool, const float* __restrict__ ptemp,
    const float* __restrict__ w_mlp, const float* __restrict__ b_mlp,
    const float* __restrict__ arc_w, float* __restrict__ out,
    __hip_bfloat16* __restrict__ w_in_bf, __hip_bfloat16* __restrict__ w_out_bf,
    __hip_bfloat16* __restrict__ w_mlp_bf, __hip_bfloat16* __restrict__ parts_bf,
    __hip_bfloat16* __restrict__ qkv_bf, __hip_bfloat16* __restrict__ obuf_bf,
    float* __restrict__ aout, float* __restrict__ pmlp) {
  cg::grid_group gg = cg::this_grid();
  __shared__ __align__(16) char smraw[SMB];
  int t = threadIdx.x, blk = blockIdx.x, nb = gridDim.x;

  // P0: select+LN1 (blk 0..63) | weight casts (blk 64..)
  if (blk < 64) {
    dev_select_ln1(blk, t, hidden, attns, ln1_g, ln1_b, parts_bf, smraw);
  } else {
    for (int i = (blk - 64) * 256 + t; i < 737280; i += (nb - 64) * 256) {
      const float* src; __hip_bfloat16* dst; int off;
      if (i < 442368) { src = w_in; dst = w_in_bf; off = i; }
      else if (i < 589824) { src = w_out; dst = w_out_bf; off = i - 442368; }
      else { src = w_mlp; dst = w_mlp_bf; off = i - 589824; }
      float4 v = ((const float4*)src)[off];
      union { unsigned short u[4]; ushort4 v4; } p;
      p.u[0] = bf16_bits(v.x); p.u[1] = bf16_bits(v.y);
      p.u[2] = bf16_bits(v.z); p.u[3] = bf16_bits(v.w);
      ((ushort4*)dst)[off] = p.v4;
    }
  }
  gg.sync();
  // P1: qkv = parts @ w_in^T + b_in (768x2304x768) -> bf16
  for (int tile = blk; tile < 432; tile += nb)
    gemm_tile64<0, 1>(parts_bf, w_in_bf, b_in, (void*)qkv_bf, 2304, 768,
                      tile % 12, tile / 12, t);
  gg.sync();
  // P2: attention (768 tasks)
  for (int task = blk; task < 768; task += nb)
    dev_attn(task, t, qkv_bf, obuf_bf, smraw);
  gg.sync();
  // P3: attn_out = o @ w_out^T + b_out (768x768x768) -> f32
  for (int tile = blk; tile < 144; tile += nb)
    gemm_tile64<0, 0>(obuf_bf, w_out_bf, b_out, (void*)aout, 768, 768,
                      tile % 12, tile / 12, t);
  gg.sync();
  // P4: LN2 + pool + MLP (64 tasks)
  for (int b = blk; b < 64; b += nb)
    dev_head(b, t, aout, ln2_g, ln2_b, w_pool, b_pool, ptemp, w_mlp_bf, b_mlp,
             pmlp, smraw);
  gg.sync();
  // P5: fusion + ArcFace (b = blk&63; cblk strided by nb/64)
  {
    int b = blk & 63;
    float rnf = dev_arc_load(b, t, hidden, pmlp, smraw);
    for (int cblk = blk >> 6; cblk < 25; cblk += (nb >> 6))
      dev_arc_cblk(cblk, b, rnf, t, arc_w, labels, out, smraw);
  }
}

// ================= fallback kernels (verified R4 pipeline) ==================
__global__ __launch_bounds__(256) void kf_front(
    const float* __restrict__ hidden, const float* __restrict__ attns,
    const float* __restrict__ g, const float* __restrict__ be,
    const float* __restrict__ w1, const float* __restrict__ w2,
    const float* __restrict__ w3, __hip_bfloat16* __restrict__ o1,
    __hip_bfloat16* __restrict__ o2, __hip_bfloat16* __restrict__ o3,
    __hip_bfloat16* __restrict__ parts) {
  __shared__ __align__(16) char smraw[2048];
  int t = threadIdx.x, bi = blockIdx.x;
  if (bi >= 64) {
    int i = (bi - 64) * 256 + t;
    const float* src; __hip_bfloat16* dst; int off;
    if (i < 442368) { src = w1; dst = o1; off = i; }
    else if (i < 589824) { src = w2; dst = o2; off = i - 442368; }
    else { src = w3; dst = o3; off = i - 589824; }
    float4 v = ((const float4*)src)[off];
    union { unsigned short u[4]; ushort4 v4; } p;
    p.u[0] = bf16_bits(v.x); p.u[1] = bf16_bits(v.y);
    p.u[2] = bf16_bits(v.z); p.u[3] = bf16_bits(v.w);
    ((ushort4*)dst)[off] = p.v4;
    return;
  }
  dev_select_ln1(bi, t, hidden, attns, g, be, parts, smraw);
}

template <int RELU, int OUTBF>
__global__ __launch_bounds__(256) void kf_gemm(
    const __hip_bfloat16* __restrict__ A, const __hip_bfloat16* __restrict__ W,
    const float* __restrict__ bias, void* __restrict__ Cd, int Nn, int Kk) {
  gemm_tile64<RELU, OUTBF>(A, W, bias, Cd, Nn, Kk, blockIdx.y, blockIdx.x,
                           threadIdx.x);
}

__global__ __launch_bounds__(256) void kf_attn(
    const __hip_bfloat16* __restrict__ qkv, __hip_bfloat16* __restrict__ o) {
  __shared__ __align__(16) char smraw[9792];
  dev_attn(blockIdx.x, threadIdx.x, qkv, o, smraw);
}

__global__ __launch_bounds__(256) void kf_head(
    const float* __restrict__ aout, const float* __restrict__ g,
    const float* __restrict__ be, const float* __restrict__ wp,
    const float* __restrict__ bp, const float* __restrict__ ptemp,
    const __hip_bfloat16* __restrict__ wmlp, const float* __restrict__ bmlp,
    float* __restrict__ pmlp) {
  __shared__ __align__(16) char smraw[SMB];
  dev_head(blockIdx.x, threadIdx.x, aout, g, be, wp, bp, ptemp, wmlp, bmlp,
           pmlp, smraw);
}

__global__ __launch_bounds__(256) void kf_arc(
    const float* __restrict__ hidden, const float* __restrict__ pmlp,
    const float* __restrict__ aw, const int* __restrict__ labels,
    float* __restrict__ out) {
  __shared__ __align__(16) char smraw[6208];
  int b = blockIdx.y, t = threadIdx.x;
  float rnf = dev_arc_load(b, t, hidden, pmlp, smraw);
  dev_arc_cblk(blockIdx.x, b, rnf, t, aw, labels, out, smraw);
}

extern "C" void kernel_launch(void* const* d_in, const int* in_sizes, int n_in,
                              void* d_out, int out_size, void* d_ws, size_t ws_size,
                              hipStream_t stream) {
  const float* hidden = (const float*)d_in[0];
  const float* attns  = (const float*)d_in[1];
  const int*   labels = (const int*)d_in[2];
  const float* ln1_g  = (const float*)d_in[3];
  const float* ln1_b  = (const float*)d_in[4];
  const float* w_in   = (const float*)d_in[5];
  const float* b_in   = (const float*)d_in[6];
  const float* w_out  = (const float*)d_in[7];
  const float* b_out  = (const float*)d_in[8];
  const float* ln2_g  = (const float*)d_in[9];
  const float* ln2_b  = (const float*)d_in[10];
  const float* w_pool = (const float*)d_in[11];
  const float* b_pool = (const float*)d_in[12];
  const float* ptemp  = (const float*)d_in[13];
  const float* w_mlp  = (const float*)d_in[14];
  const float* b_mlp  = (const float*)d_in[15];
  const float* arc_w  = (const float*)d_in[16];
  float* outp = (float*)d_out;

  float* F = (float*)d_ws;
  float* reg1 = F;                                            // 884736 (qkv_bf | aout)
  float* pmlp = F + 884736;                                   // 49152
  __hip_bfloat16* parts_bf = (__hip_bfloat16*)(F + 933888);   // 589824 bf16
  __hip_bfloat16* w_in_bf  = (__hip_bfloat16*)(F + 1228800);  // 1769472 bf16
  __hip_bfloat16* w_out_bf = (__hip_bfloat16*)(F + 2113536);  // 589824 bf16
  __hip_bfloat16* w_mlp_bf = (__hip_bfloat16*)(F + 2408448);  // 589824 bf16
  __hip_bfloat16* qkv_bf = (__hip_bfloat16*)reg1;  // dead after P2
  float* aout = reg1;                              // written in P3
  __hip_bfloat16* obuf_bf = parts_bf;              // parts dead after P1

  // size the cooperative grid from the runtime's occupancy answer
  int dev = 0;
  hipGetDevice(&dev);
  int nCU = 256;
  hipDeviceGetAttribute(&nCU, hipDeviceAttributeMultiprocessorCount, dev);
  int occ = 0;
  hipOccupancyMaxActiveBlocksPerMultiprocessor(&occ, (const void*)k_mega, 256, 0);
  long cap = (long)occ * (long)nCU;
  int grid = (int)(cap > 512 ? 512 : cap);
  grid = (grid / 64) * 64;  // P5 requires multiple of 64

  hipError_t rc = hipErrorUnknown;
  if (grid >= 128) {
    void* args[] = {
        (void*)&hidden, (void*)&attns, (void*)&labels, (void*)&ln1_g,
        (void*)&ln1_b, (void*)&w_in, (void*)&b_in, (void*)&w_out,
        (void*)&b_out, (void*)&ln2_g, (void*)&ln2_b, (void*)&w_pool,
        (void*)&b_pool, (void*)&ptemp, (void*)&w_mlp, (void*)&b_mlp,
        (void*)&arc_w, (void*)&outp, (void*)&w_in_bf, (void*)&w_out_bf,
        (void*)&w_mlp_bf, (void*)&parts_bf, (void*)&qkv_bf, (void*)&obuf_bf,
        (void*)&aout, (void*)&pmlp};
    rc = hipLaunchCooperativeKernel((void*)k_mega, dim3(grid), dim3(256), args,
                                    0, stream);
  }
  if (rc != hipSuccess) {
    // fallback: verified 5-kernel chain
    kf_front<<<2944, 256, 0, stream>>>(hidden, attns, ln1_g, ln1_b, w_in, w_out,
                                       w_mlp, w_in_bf, w_out_bf, w_mlp_bf,
                                       parts_bf);
    kf_gemm<0, 1><<<dim3(36, 12), 256, 0, stream>>>(parts_bf, w_in_bf, b_in,
                                                    (void*)qkv_bf, 2304, 768);
    kf_attn<<<768, 256, 0, stream>>>(qkv_bf, obuf_bf);
    kf_gemm<0, 0><<<dim3(12, 12), 256, 0, stream>>>(obuf_bf, w_out_bf, b_out,
                                                    (void*)aout, 768, 768);
    kf_head<<<64, 256, 0, stream>>>(aout, ln2_g, ln2_b, w_pool, b_pool, ptemp,
                                    w_mlp_bf, b_mlp, pmlp);
    kf_arc<<<dim3(25, 64), 256, 0, stream>>>(hidden, pmlp, arc_w, labels, outp);
  }
}

// Round 7
// 90.788 us; speedup vs baseline: 4.3545x; 4.3545x over previous
//
#include <hip/hip_runtime.h>
#include <hip/hip_bf16.h>
#include <float.h>
#include <math.h>

#define BB 64
#define NNtok 197
#define DD 768
#define HH 12
#define PP 12
#define CC 200
#define NPATCH 196

typedef short bf16x8 __attribute__((ext_vector_type(8)));
typedef float f32x4 __attribute__((ext_vector_type(4)));

__device__ __forceinline__ unsigned short bf16_bits(float x) {
  __hip_bfloat16 h = __float2bfloat16(x);
  return *reinterpret_cast<unsigned short*>(&h);
}
__device__ __forceinline__ float u2f(unsigned int u) {
  union { unsigned int u; float f; } cv; cv.u = u; return cv.f;
}
__device__ __forceinline__ float bfu(unsigned short us) {
  union { unsigned int u; float f; } cv; cv.u = ((unsigned int)us) << 16; return cv.f;
}

// ================= K1: select+top12+LN1 (blk<64) | weight casts =============
__global__ __launch_bounds__(256) void k1_front(
    const float* __restrict__ hidden, const float* __restrict__ attns,
    const float* __restrict__ g, const float* __restrict__ be,
    const float* __restrict__ w1, const float* __restrict__ w2,
    const float* __restrict__ w3, __hip_bfloat16* __restrict__ o1,
    __hip_bfloat16* __restrict__ o2, __hip_bfloat16* __restrict__ o3,
    __hip_bfloat16* __restrict__ parts) {
  int t = threadIdx.x, bi = blockIdx.x;
  if (bi >= 64) {
    for (int i = (bi - 64) * 256 + t; i < 737280; i += 256 * 256) {
      const float* src; __hip_bfloat16* dst; int off;
      if (i < 442368) { src = w1; dst = o1; off = i; }
      else if (i < 589824) { src = w2; dst = o2; off = i - 442368; }
      else { src = w3; dst = o3; off = i - 589824; }
      float4 v = ((const float4*)src)[off];
      union { unsigned short u[4]; ushort4 v4; } p;
      p.u[0] = bf16_bits(v.x); p.u[1] = bf16_bits(v.y);
      p.u[2] = bf16_bits(v.z); p.u[3] = bf16_bits(v.w);
      ((ushort4*)dst)[off] = p.v4;
    }
    return;
  }
  int b = bi;
  __shared__ float sc[256];
  __shared__ int sel_s[PP];
  int wv = t >> 6, ln = t & 63;
  float acc = -FLT_MAX;
  if (t < NPATCH) {
    acc = 0.f;
#pragma unroll
    for (int l = 0; l < 4; l++) {
      float part = 0.f;
#pragma unroll
      for (int h = 0; h < HH; h++) {
        size_t base = (size_t)((l * BB + b) * HH + h) * ((size_t)NNtok * NNtok);
        part += attns[base + 1 + t];
      }
      acc += part * (1.f / 12.f);
    }
    acc *= 0.25f;
  }
  sc[t] = acc;
  __syncthreads();
  if (t < 64) {
    float v[4]; int idx[4];
#pragma unroll
    for (int j = 0; j < 4; j++) { idx[j] = t + j * 64; v[j] = sc[idx[j]]; }
    for (int it = 0; it < PP; ++it) {
      float bv = v[0]; int bidx = idx[0];
#pragma unroll
      for (int j = 1; j < 4; j++)
        if (v[j] > bv || (v[j] == bv && idx[j] < bidx)) { bv = v[j]; bidx = idx[j]; }
      float cv = bv; int ci = bidx;
#pragma unroll
      for (int off = 32; off > 0; off >>= 1) {
        float ov = __shfl_xor(cv, off); int oi = __shfl_xor(ci, off);
        if (ov > cv || (ov == cv && oi < ci)) { cv = ov; ci = oi; }
      }
      if (t == 0) sel_s[it] = ci;
#pragma unroll
      for (int j = 0; j < 4; j++)
        if (idx[j] == ci) v[j] = -FLT_MAX;
    }
  }
  __syncthreads();
#pragma unroll
  for (int q = 0; q < 3; q++) {
    int i = wv * 3 + q;
    const float* row = hidden + ((size_t)b * NNtok + 1 + sel_s[i]) * DD;
    float x[12], s1 = 0.f, s2 = 0.f;
#pragma unroll
    for (int k = 0; k < 12; k++) {
      x[k] = row[ln + 64 * k];
      s1 += x[k]; s2 += x[k] * x[k];
    }
#pragma unroll
    for (int off = 32; off > 0; off >>= 1) {
      s1 += __shfl_xor(s1, off); s2 += __shfl_xor(s2, off);
    }
    float m = s1 * (1.f / DD);
    float rstd = rsqrtf(s2 * (1.f / DD) - m * m + 1e-5f);
    __hip_bfloat16* outp_ = parts + ((size_t)b * PP + i) * DD;
#pragma unroll
    for (int k = 0; k < 12; k++) {
      int d = ln + 64 * k;
      outp_[d] = __float2bfloat16((x[k] - m) * rstd * g[d] + be[d]);
    }
  }
}

// ====== K2: per (b,hg): qkv-slice GEMM + 3-head attention + partial wout ====
__global__ __launch_bounds__(256) void k2_mid(
    const __hip_bfloat16* __restrict__ parts, const __hip_bfloat16* __restrict__ w_in_bf,
    const float* __restrict__ b_in, const __hip_bfloat16* __restrict__ w_out_bf,
    float* __restrict__ part_ws) {
  int bi = blockIdx.x;
  int b = bi >> 2, hg = bi & 3;
  int t = threadIdx.x;
  int wave = t >> 6, lane = t & 63, lr = lane & 15, kg = lane >> 4;
  __shared__ __align__(16) unsigned short qkv3[3][16][192];  // bf16 bits
  __shared__ __align__(16) unsigned short o3[16][192];
  __shared__ float scores[432];

  // ---- step A: qkv slice = parts16(b) @ W_in[slice]^T ----
  int pr = lr < 12 ? lr : 11;  // pad rows 12-15 (outputs discarded)
  const __hip_bfloat16* Ab = parts + ((size_t)b * 12 + pr) * DD + kg * 8;
  int wrow[9];
#pragma unroll
  for (int nf = 0; nf < 9; nf++) {
    int lc = wave * 144 + nf * 16 + lr;      // 0..575
    int s = lc / 192, d2 = lc - s * 192;
    wrow[nf] = s * 768 + hg * 192 + d2;      // row of w_in (2304x768)
  }
  f32x4 acc[9];
#pragma unroll
  for (int nf = 0; nf < 9; nf++) { acc[nf][0]=0.f; acc[nf][1]=0.f; acc[nf][2]=0.f; acc[nf][3]=0.f; }
  for (int k0 = 0; k0 < 768; k0 += 32) {
    bf16x8 af = *(const bf16x8*)(Ab + k0);
    bf16x8 wf[9];
#pragma unroll
    for (int nf = 0; nf < 9; nf++)
      wf[nf] = *(const bf16x8*)(w_in_bf + (size_t)wrow[nf] * DD + kg * 8 + k0);
#pragma unroll
    for (int nf = 0; nf < 9; nf++)
      acc[nf] = __builtin_amdgcn_mfma_f32_16x16x32_bf16(af, wf[nf], acc[nf], 0, 0, 0);
  }
#pragma unroll
  for (int nf = 0; nf < 9; nf++) {
    int lc = wave * 144 + nf * 16 + lr;
    int s = lc / 192, d2 = lc - s * 192;
    float bv = b_in[s * 768 + hg * 192 + d2];
#pragma unroll
    for (int r = 0; r < 4; r++) {
      int p = kg * 4 + r;
      qkv3[s][p][d2] = bf16_bits(acc[nf][r] + bv);
    }
  }
  __syncthreads();

  // ---- attention for 3 local heads ----
  for (int e = t; e < 432; e += 256) {
    int h = e / 144, rem = e - h * 144;
    int i = rem / 12, j = rem - i * 12;
    float s = 0.f;
#pragma unroll
    for (int d = 0; d < 64; d++)
      s += bfu(qkv3[0][i][h * 64 + d]) * bfu(qkv3[1][j][h * 64 + d]);
    scores[e] = s * 0.125f;
  }
  __syncthreads();
  if (t < 36) {
    int h = t / 12, i = t - h * 12;
    float* row = scores + h * 144 + i * 12;
    float m = -FLT_MAX;
#pragma unroll
    for (int j = 0; j < 12; j++) m = fmaxf(m, row[j]);
    float e2[12], sum = 0.f;
#pragma unroll
    for (int j = 0; j < 12; j++) { e2[j] = expf(row[j] - m); sum += e2[j]; }
    float inv = 1.f / sum;
#pragma unroll
    for (int j = 0; j < 12; j++) row[j] = e2[j] * inv;
  }
  __syncthreads();
  for (int o = t; o < 2304; o += 256) {
    int i = o / 192, d2 = o - i * 192;
    int h = d2 >> 6;
    float s = 0.f;
#pragma unroll
    for (int j = 0; j < 12; j++)
      s += scores[h * 144 + i * 12 + j] * bfu(qkv3[2][j][d2]);
    o3[i][d2] = bf16_bits(s);
  }
  __syncthreads();

  // ---- step C: partial wout: part(12x768) = o3(12x192) @ W_out[:, slice]^T
  f32x4 acc2[12];
#pragma unroll
  for (int jf = 0; jf < 12; jf++) { acc2[jf][0]=0.f; acc2[jf][1]=0.f; acc2[jf][2]=0.f; acc2[jf][3]=0.f; }
  const unsigned short* Ob = &o3[0][0] + lr * 192 + kg * 8;
  for (int k0 = 0; k0 < 192; k0 += 32) {
    bf16x8 af = *(const bf16x8*)(Ob + k0);
    bf16x8 wf[12];
#pragma unroll
    for (int jf = 0; jf < 12; jf++) {
      int j = wave * 192 + jf * 16 + lr;
      wf[jf] = *(const bf16x8*)(w_out_bf + (size_t)j * DD + hg * 192 + kg * 8 + k0);
    }
#pragma unroll
    for (int jf = 0; jf < 12; jf++)
      acc2[jf] = __builtin_amdgcn_mfma_f32_16x16x32_bf16(af, wf[jf], acc2[jf], 0, 0, 0);
  }
#pragma unroll
  for (int jf = 0; jf < 12; jf++) {
    int j = wave * 192 + jf * 16 + lr;
#pragma unroll
    for (int r = 0; r < 4; r++) {
      int p = kg * 4 + r;
      if (p < 12)
        part_ws[(((size_t)b * 4 + hg) * 12 + p) * DD + j] = acc2[jf][r];
    }
  }
}

// ====== K3: per (b,q4): reduce partials + LN2 + pool + MLP slice ============
__global__ __launch_bounds__(256) void k3_back(
    const float* __restrict__ part_ws, const float* __restrict__ b_out,
    const float* __restrict__ g, const float* __restrict__ be,
    const float* __restrict__ wp, const float* __restrict__ bp,
    const float* __restrict__ ptemp, const __hip_bfloat16* __restrict__ wmlp,
    const float* __restrict__ bmlp, float* __restrict__ pmlp) {
  int bi = blockIdx.x;
  int b = bi >> 2, q4 = bi & 3;
  int t = threadIdx.x, wv = t >> 6, ln = t & 63;
  __shared__ float a12[12 * 768];
  __shared__ float raww_s[12];
  __shared__ float pfeat[768];
  for (int u = t; u < 9216; u += 256) {
    int j = u % 768;
    float s = b_out[j];
#pragma unroll
    for (int hg = 0; hg < 4; hg++)
      s += part_ws[(((size_t)b * 4 + hg) * 12) * DD + u];
    a12[u] = s;
  }
  __syncthreads();
#pragma unroll
  for (int q = 0; q < 3; q++) {
    int r = wv * 3 + q;
    float x[12], s1 = 0.f, s2 = 0.f;
#pragma unroll
    for (int k = 0; k < 12; k++) {
      x[k] = a12[r * 768 + ln + 64 * k];
      s1 += x[k]; s2 += x[k] * x[k];
    }
#pragma unroll
    for (int off = 32; off > 0; off >>= 1) {
      s1 += __shfl_xor(s1, off); s2 += __shfl_xor(s2, off);
    }
    float m = s1 * (1.f / DD);
    float rstd = rsqrtf(s2 * (1.f / DD) - m * m + 1e-5f);
    float pl = 0.f;
#pragma unroll
    for (int k = 0; k < 12; k++) {
      int d = ln + 64 * k;
      float y = (x[k] - m) * rstd * g[d] + be[d];
      a12[r * 768 + d] = y;
      pl += y * wp[d];
    }
#pragma unroll
    for (int off = 32; off > 0; off >>= 1) pl += __shfl_xor(pl, off);
    if (ln == 0) raww_s[r] = pl + bp[0];
  }
  __syncthreads();
  float wts[12];
  {
    float inv = 1.f / fmaxf(ptemp[0], 0.3f);
    float z[12], mx = -FLT_MAX;
#pragma unroll
    for (int p = 0; p < 12; p++) { z[p] = raww_s[p] * inv; mx = fmaxf(mx, z[p]); }
    float s = 0.f;
#pragma unroll
    for (int p = 0; p < 12; p++) { z[p] = expf(z[p] - mx); s += z[p]; }
    float is = 1.f / s;
#pragma unroll
    for (int p = 0; p < 12; p++) wts[p] = z[p] * is;
  }
  for (int d = t; d < 768; d += 256) {
    float s = 0.f;
#pragma unroll
    for (int p = 0; p < 12; p++) s += a12[p * 768 + d] * wts[p];
    pfeat[d] = s;
  }
  __syncthreads();
  if (t < 192) {
    int j = q4 * 192 + t;
    const uint4* wr = (const uint4*)(wmlp + (size_t)j * DD);
    float acc2 = bmlp[j];
    for (int k = 0; k < 96; k++) {
      uint4 w4 = wr[k];
      const float* pf = &pfeat[k * 8];
      acc2 += pf[0] * u2f(w4.x << 16) + pf[1] * u2f(w4.x & 0xFFFF0000u)
            + pf[2] * u2f(w4.y << 16) + pf[3] * u2f(w4.y & 0xFFFF0000u)
            + pf[4] * u2f(w4.z << 16) + pf[5] * u2f(w4.z & 0xFFFF0000u)
            + pf[6] * u2f(w4.w << 16) + pf[7] * u2f(w4.w & 0xFFFF0000u);
    }
    pmlp[(size_t)b * DD + j] = fmaxf(acc2, 0.f);
  }
}

// ====== K4: fusion norm + arc_w norms + ArcFace, 16 classes/block ===========
__global__ __launch_bounds__(256) void k4_arc(
    const float* __restrict__ hidden, const float* __restrict__ pmlp,
    const float* __restrict__ aw, const int* __restrict__ labels,
    float* __restrict__ out) {
  int cb = blockIdx.x, b = blockIdx.y, t = threadIdx.x;
  int wv = t >> 6, ln = t & 63;
  __shared__ float4 fs4[384];
  __shared__ float a4[4];
  const float4* cls4 = (const float4*)(hidden + (size_t)b * NNtok * DD);
  const float4* pm4 = (const float4*)(pmlp + (size_t)b * DD);
  for (int u = t; u < 384; u += 256) fs4[u] = (u < 192) ? cls4[u] : pm4[u - 192];
  __syncthreads();
  float s = 0.f;
  for (int u = t; u < 384; u += 256) {
    float4 v = fs4[u];
    s += v.x * v.x + v.y * v.y + v.z * v.z + v.w * v.w;
  }
#pragma unroll
  for (int off = 32; off > 0; off >>= 1) s += __shfl_xor(s, off);
  if (ln == 0) a4[wv] = s;
  __syncthreads();
  float rnf = rsqrtf(a4[0] + a4[1] + a4[2] + a4[3]);
  int lab = labels[b];
  const float cos_m = 0.8775825618903728f, sin_m = 0.479425538604203f;
  const float th = -0.8775825618903728f, mm = 0.2397127693021015f;
#pragma unroll
  for (int ci = 0; ci < 4; ci++) {
    int c = cb * 16 + ci * 4 + wv;
    if (c < CC) {
      const float4* wr = (const float4*)(aw + (size_t)c * 1536);
      float acc = 0.f, nw = 0.f;
#pragma unroll
      for (int k = 0; k < 6; k++) {
        float4 a = fs4[ln + 64 * k];
        float4 w = wr[ln + 64 * k];
        acc += a.x * w.x + a.y * w.y + a.z * w.z + a.w * w.w;
        nw += w.x * w.x + w.y * w.y + w.z * w.z + w.w * w.w;
      }
#pragma unroll
      for (int off = 32; off > 0; off >>= 1) {
        acc += __shfl_xor(acc, off); nw += __shfl_xor(nw, off);
      }
      if (ln == 0) {
        float cosv = acc * rsqrtf(nw) * rnf;
        float s2 = 1.f - cosv * cosv;
        s2 = fminf(fmaxf(s2, 0.f), 1.f);
        float sinv = sqrtf(s2);
        float phi = cosv * cos_m - sinv * sin_m;
        phi = (cosv > th) ? phi : (cosv - mm);
        out[(size_t)b * CC + c] = ((c == lab) ? phi : cosv) * 30.f;
      }
    }
  }
}

extern "C" void kernel_launch(void* const* d_in, const int* in_sizes, int n_in,
                              void* d_out, int out_size, void* d_ws, size_t ws_size,
                              hipStream_t stream) {
  const float* hidden = (const float*)d_in[0];
  const float* attns  = (const float*)d_in[1];
  const int*   labels = (const int*)d_in[2];
  const float* ln1_g  = (const float*)d_in[3];
  const float* ln1_b  = (const float*)d_in[4];
  const float* w_in   = (const float*)d_in[5];
  const float* b_in   = (const float*)d_in[6];
  const float* w_out  = (const float*)d_in[7];
  const float* b_out  = (const float*)d_in[8];
  const float* ln2_g  = (const float*)d_in[9];
  const float* ln2_b  = (const float*)d_in[10];
  const float* w_pool = (const float*)d_in[11];
  const float* b_pool = (const float*)d_in[12];
  const float* ptemp  = (const float*)d_in[13];
  const float* w_mlp  = (const float*)d_in[14];
  const float* b_mlp  = (const float*)d_in[15];
  const float* arc_w  = (const float*)d_in[16];
  float* outp = (float*)d_out;

  float* F = (float*)d_ws;
  float* part_ws = F;                                          // 2359296 f32
  float* pmlp    = F + 2359296;                                // 49152
  __hip_bfloat16* parts_bf = (__hip_bfloat16*)(F + 2408448);   // 589824 bf16
  __hip_bfloat16* w_in_bf  = (__hip_bfloat16*)(F + 2703360);   // 1769472 bf16
  __hip_bfloat16* w_out_bf = (__hip_bfloat16*)(F + 3588096);   // 589824 bf16
  __hip_bfloat16* w_mlp_bf = (__hip_bfloat16*)(F + 3883008);   // 589824 bf16

  k1_front<<<320, 256, 0, stream>>>(hidden, attns, ln1_g, ln1_b, w_in, w_out,
                                    w_mlp, w_in_bf, w_out_bf, w_mlp_bf, parts_bf);
  k2_mid<<<256, 256, 0, stream>>>(parts_bf, w_in_bf, b_in, w_out_bf, part_ws);
  k3_back<<<256, 256, 0, stream>>>(part_ws, b_out, ln2_g, ln2_b, w_pool, b_pool,
                                   ptemp, w_mlp_bf, b_mlp, pmlp);
  k4_arc<<<dim3(13, BB), 256, 0, stream>>>(hidden, pmlp, arc_w, labels, outp);
}